// Round 4
// baseline (7944.753 us; speedup 1.0000x reference)
//
#include <hip/hip_runtime.h>

// Persistent batched-GRU kernel for MI355X (gfx950), round 13.
// r12 (two-group in-wave pipeline) worked: 9355->7942us, MFMA+VALU overlap
// established; VALU is now the tall pole (3483 of 5502 cyc/interval).
// Round-13: re-apply the r10 VALU diet ON TOP of the r12 pipeline (diet only
// touches gate math, not MFMA chains, so r10's ILP regression can't recur):
//  - prep_w pre-scales W_hh rows: r,z * -log2e ; n * +2*log2e
//  - per-lane consts pre-scaled; gate biases preloaded into MFMA accs
//  - sigmoid = rcp(1+exp2(fma)), tanh = 1-2*rcp(1+exp2(fma))
//  - h publish via v_cvt_pk_bf16_f32 pairs
// Carried from r12: 512 blocks x 32 rows (groups P/Q), weights shared across
// groups, z_j1/n_j1 frags in LDS (128 KB), 128 weight VGPRs, one lgkm-only
// barrier per interval, DPP out-reduce, direct global x loads / out stores.

#define B_TOTAL 16384
#define T_LEN   1024
#define GRPROWS 16
#define M_ROWS  32
#define NBLOCKS (B_TOTAL / M_ROWS)      // 512 blocks; 2 sequential per CU
#define NTHREADS 512                    // 8 waves
#define LDSW    264                     // h row stride in shorts

typedef short short8 __attribute__((ext_vector_type(8)));
typedef float f32x4  __attribute__((ext_vector_type(4)));

__device__ unsigned short g_wsw[196608];   // swizzled, PRE-SCALED bf16 W_hh

__device__ __forceinline__ unsigned short f2b(float f) {
  unsigned u = __builtin_bit_cast(unsigned, f);
  u += 0x7fffu + ((u >> 16) & 1u);
  return (unsigned short)(u >> 16);
}
__device__ __forceinline__ unsigned cvt_pk_bf16(float lo, float hi) {
  unsigned r;
  asm("v_cvt_pk_bf16_f32 %0, %1, %2" : "=v"(r) : "v"(lo), "v"(hi));
  return r;
}
// sum over a 16-lane DPP row; result valid in the LAST lane (r16==15)
__device__ __forceinline__ float dpp_red16(float v) {
  int x = __builtin_bit_cast(int, v);
  v += __builtin_bit_cast(float, __builtin_amdgcn_update_dpp(0, x, 0x118, 0xF, 0xF, true)); // row_shr:8
  x = __builtin_bit_cast(int, v);
  v += __builtin_bit_cast(float, __builtin_amdgcn_update_dpp(0, x, 0x114, 0xF, 0xF, true)); // row_shr:4
  x = __builtin_bit_cast(int, v);
  v += __builtin_bit_cast(float, __builtin_amdgcn_update_dpp(0, x, 0x112, 0xF, 0xF, true)); // row_shr:2
  x = __builtin_bit_cast(int, v);
  v += __builtin_bit_cast(float, __builtin_amdgcn_update_dpp(0, x, 0x111, 0xF, 0xF, true)); // row_shr:1
  return v;
}
// barrier draining LDS only (no vmcnt(0): global stores stay in flight)
__device__ __forceinline__ void barrier_lgkm() {
  asm volatile("s_waitcnt lgkmcnt(0)\n\ts_barrier" ::: "memory");
}

// Swizzle W_hh (768x256 f32 row-major) into fragment-major bf16, PRE-SCALED:
// rows 0..511 (r,z) * -log2e ; rows 512..767 (n) * 2*log2e.
// dst[((nt*8 + ks)*64 + lane)*8 + e] = bf16(s * W[nt*16 + (lane&15)][ks*32 + (lane>>4)*8 + e])
__global__ void prep_w(const float* __restrict__ w_hh) {
  int tid  = blockIdx.x * 256 + threadIdx.x;     // 196608 total
  int e    = tid & 7;
  int lane = (tid >> 3) & 63;
  int ks   = (tid >> 9) & 7;
  int nt   = tid >> 12;
  int row  = nt * 16 + (lane & 15);
  int col  = ks * 32 + (lane >> 4) * 8 + e;
  float s  = (row < 512) ? -1.44269504f : 2.88539008f;
  g_wsw[tid] = f2b(w_hh[row * 256 + col] * s);
}

#define MF(A, B, C) __builtin_amdgcn_mfma_f32_16x16x32_bf16((A), (B), (C), 0, 0, 0)

// one K-step for acc-set P## (6 chains): 4 register B-frags + 2 LDS B-frags,
// EXTRA = interleaved gate work for the other group
#define KSTEP(P, AR, KS, EXTRA)  {                                             \
    short8 a_  = *(const short8*)((AR) + (KS)*32);                             \
    short8 z1_ = *(const short8*)&w_lds[wz1b + (KS)*512];                      \
    short8 n1_ = *(const short8*)&w_lds[wn1b + (KS)*512];                      \
    P##00 = MF(a_, wrr0[KS], P##00);                                           \
    P##01 = MF(a_, wrr1[KS], P##01);                                           \
    P##10 = MF(a_, wrz0[KS], P##10);                                           \
    P##11 = MF(a_, z1_,      P##11);                                           \
    P##20 = MF(a_, wrn0[KS], P##20);                                           \
    P##21 = MF(a_, n1_,      P##21);                                           \
    EXTRA                                                                      \
  }

// one gate element, DIET math (accs carry fused scaled biases).
// AC=acc prefix, HR=h carry, XV=x vec, VO=out accum, J=col-tile, I=row-in-quad
#define GEL(AC, HR, XV, VO, J, I) {                                            \
    float t_r = __builtin_fmaf(XV[I], swr[J], AC##0##J[I]);                    \
    float rg_ = __builtin_amdgcn_rcpf(1.0f + __builtin_amdgcn_exp2f(t_r));     \
    float t_z = __builtin_fmaf(XV[I], swz[J], AC##1##J[I]);                    \
    float zg_ = __builtin_amdgcn_rcpf(1.0f + __builtin_amdgcn_exp2f(t_z));     \
    float t_n = __builtin_fmaf(XV[I], swn[J], sbni[J]);                        \
    float yn_ = __builtin_fmaf(rg_, AC##2##J[I], t_n);                         \
    float rn_ = __builtin_amdgcn_rcpf(1.0f + __builtin_amdgcn_exp2f(yn_));     \
    float ng_ = __builtin_fmaf(-2.0f, rn_, 1.0f);                              \
    float hn_ = __builtin_fmaf(zg_, HR[J][I] - ng_, ng_);                      \
    HR[J][I] = hn_;                                                            \
    VO[I] += fmaxf(hn_, 0.0f)*wo[J];                                           \
  }

// publish rows (I0, I0+1) of column cc[J] for group HG as a packed bf16 pair
#define PUBP(HR, HG, J, I0) {                                                  \
    unsigned pk_ = cvt_pk_bf16(HR[J][I0], HR[J][(I0)+1]);                      \
    h_lds[HG][hwb[J] + (I0)*LDSW]     = (unsigned short)pk_;                   \
    h_lds[HG][hwb[J] + ((I0)+1)*LDSW] = (unsigned short)(pk_ >> 16);           \
  }

#define VORED(VO, G, S) {                                                      \
    _Pragma("unroll") for (int i_ = 0; i_ < 4; ++i_) VO[i_] = dpp_red16(VO[i_]); \
    if (r16 == 15) {                                                           \
      _Pragma("unroll") for (int i_ = 0; i_ < 4; ++i_)                         \
        op[G][(S)&1][w][q*4 + i_] = VO[i_];                                    \
    } }

// finalize out(G, S): 16 threads starting at TLO sum 8 wave partials + store
#define FIN(G, S, TLO)                                                         \
  if (tid >= (TLO) && tid < (TLO) + 16) {                                      \
    float o_ = bo;                                                             \
    _Pragma("unroll") for (int ww_ = 0; ww_ < 8; ++ww_)                        \
      o_ += op[G][(S)&1][ww_][tid - (TLO)];                                    \
    out[(base + (G)*GRPROWS + (tid - (TLO)))*T_LEN + (S)] = o_;                \
  }

// acc init: fused scaled biases (r in acc0, z in acc1, n-hh in acc2)
#define ACCB(P) {                                                              \
    P##00 = (f32x4){sbr[0],sbr[0],sbr[0],sbr[0]};                              \
    P##01 = (f32x4){sbr[1],sbr[1],sbr[1],sbr[1]};                              \
    P##10 = (f32x4){sbz[0],sbz[0],sbz[0],sbz[0]};                              \
    P##11 = (f32x4){sbz[1],sbz[1],sbz[1],sbz[1]};                              \
    P##20 = (f32x4){sbnh[0],sbnh[0],sbnh[0],sbnh[0]};                          \
    P##21 = (f32x4){sbnh[1],sbnh[1],sbnh[1],sbnh[1]};                          \
  }

#define XLOAD(XV, G, S) {                                                      \
    _Pragma("unroll") for (int i_ = 0; i_ < 4; ++i_)                           \
      XV[i_] = x[(base + (G)*GRPROWS + q*4 + i_)*T_LEN + (S)];                 \
  }

__global__ __launch_bounds__(NTHREADS, 2) void gru_kernel(
    const float* __restrict__ x,
    const float* __restrict__ w_ih,
    const float* __restrict__ b_ih,
    const float* __restrict__ b_hh,
    const float* __restrict__ w_out,
    const float* __restrict__ b_out,
    float* __restrict__ out)
{
  __shared__ unsigned short h_lds[2][GRPROWS * LDSW];  // [group], 16.5 KB
  __shared__ unsigned short w_lds[16 * 8 * 512];       // z_j1/n_j1 frags, 128 KB
  __shared__ float op[2][2][8][GRPROWS];               // [group][phase][wave][row], 4 KB

  const int tid  = threadIdx.x;
  const int w    = tid >> 6;        // wave 0..7
  const int lane = tid & 63;
  const int r16  = lane & 15;
  const int q    = lane >> 4;
  const long base = (long)blockIdx.x * M_ROWS;

  for (int i = tid; i < 2 * GRPROWS * LDSW; i += NTHREADS) h_lds[0][i] = 0;  // h0 = 0 (both groups)

  // ---- stage z_j1 (gsel 0) and n_j1 (gsel 1) frags into LDS ----
  const int wz1b = ((w*2 + 0)*8)*512 + lane*8;
  const int wn1b = ((w*2 + 1)*8)*512 + lane*8;
#pragma unroll
  for (int gsel = 0; gsel < 2; ++gsel)
#pragma unroll
    for (int ks = 0; ks < 8; ++ks)
      *(short8*)&w_lds[((w*2 + gsel)*8 + ks)*512 + lane*8] =
        *(const short8*)&g_wsw[((((gsel + 1)*16 + w*2 + 1)*8 + ks)*64 + lane)*8];

  // ---- register-resident frags: r_j0, r_j1, z_j0, n_j0 (128 VGPR) ----
  short8 wrr0[8], wrr1[8], wrz0[8], wrn0[8];
#pragma unroll
  for (int ks = 0; ks < 8; ++ks) {
    wrr0[ks] = *(const short8*)&g_wsw[(((0*16 + w*2 + 0)*8 + ks)*64 + lane)*8];
    wrr1[ks] = *(const short8*)&g_wsw[(((0*16 + w*2 + 1)*8 + ks)*64 + lane)*8];
    wrz0[ks] = *(const short8*)&g_wsw[(((1*16 + w*2 + 0)*8 + ks)*64 + lane)*8];
    wrn0[ks] = *(const short8*)&g_wsw[(((2*16 + w*2 + 0)*8 + ks)*64 + lane)*8];
  }

  // per-lane constants for cols c(j) = w*32 + j*16 + r16, pre-scaled:
  // r,z: -log2e ; n: +2*log2e
  const float C1 = 1.44269504f;
  float swr[2], swz[2], swn[2], sbr[2], sbz[2], sbni[2], sbnh[2], wo[2];
  int cc[2], hwb[2];
#pragma unroll
  for (int j = 0; j < 2; ++j) {
    int c = w*32 + j*16 + r16;
    cc[j]    = c;
    hwb[j]   = (q*4)*LDSW + c;
    swr[j]   = -C1 * w_ih[c];
    swz[j]   = -C1 * w_ih[256 + c];
    swn[j]   = 2.0f * C1 * w_ih[512 + c];
    sbr[j]   = -C1 * (b_ih[c]       + b_hh[c]);
    sbz[j]   = -C1 * (b_ih[256 + c] + b_hh[256 + c]);
    sbni[j]  = 2.0f * C1 * b_ih[512 + c];
    sbnh[j]  = 2.0f * C1 * b_hh[512 + c];
    wo[j]    = w_out[c];
  }
  const float bo = b_out[0];
  const f32x4 zero4 = {0.f, 0.f, 0.f, 0.f};

  float hP[2][4], hQ[2][4];        // f32 h carry, both groups
#pragma unroll
  for (int j = 0; j < 2; ++j)
#pragma unroll
    for (int i = 0; i < 4; ++i) { hP[j][i] = 0.0f; hQ[j][i] = 0.0f; }

  const unsigned short* arP = &h_lds[0][r16*LDSW + q*8];
  const unsigned short* arQ = &h_lds[1][r16*LDSW + q*8];

  // acc sets: aP## built in A-intervals / consumed in B; aQ## vice versa
  f32x4 aP00, aP01, aP10, aP11, aP20, aP21;
  f32x4 aQ00, aQ01, aQ10, aQ11, aQ20, aQ21;

  barrier_lgkm();   // h zeros + w_lds staged

  // ---- pre-loop interval A0: MFMA(P, 0) only ----
  {
    ACCB(aP)
    KSTEP(aP, arP, 0, ) KSTEP(aP, arP, 1, ) KSTEP(aP, arP, 2, ) KSTEP(aP, arP, 3, )
    KSTEP(aP, arP, 4, ) KSTEP(aP, arP, 5, ) KSTEP(aP, arP, 6, ) KSTEP(aP, arP, 7, )
    barrier_lgkm();
  }

#pragma unroll 1
  for (int s = 0; s < T_LEN - 1; ++s) {     // s = 0..1022
    // ======== interval B(s): MFMA(Q,s) + gates(P,s) + fin(P,s-1) ========
    {
      f32x4 xvP; XLOAD(xvP, 0, s);
      if (s > 0) { FIN(0, s-1, 0) }
      ACCB(aQ)
      f32x4 voP = zero4;
      KSTEP(aQ, arQ, 0, GEL(aP, hP, xvP, voP, 0, 0))
      KSTEP(aQ, arQ, 1, GEL(aP, hP, xvP, voP, 0, 1) PUBP(hP, 0, 0, 0))
      KSTEP(aQ, arQ, 2, GEL(aP, hP, xvP, voP, 0, 2))
      KSTEP(aQ, arQ, 3, GEL(aP, hP, xvP, voP, 0, 3) PUBP(hP, 0, 0, 2))
      KSTEP(aQ, arQ, 4, GEL(aP, hP, xvP, voP, 1, 0))
      KSTEP(aQ, arQ, 5, GEL(aP, hP, xvP, voP, 1, 1) PUBP(hP, 0, 1, 0))
      KSTEP(aQ, arQ, 6, GEL(aP, hP, xvP, voP, 1, 2))
      KSTEP(aQ, arQ, 7, GEL(aP, hP, xvP, voP, 1, 3) PUBP(hP, 0, 1, 2))
      VORED(voP, 0, s)
      barrier_lgkm();
    }
    // ======== interval A(s+1): MFMA(P,s+1) + gates(Q,s) + fin(Q,s-1) ========
    {
      f32x4 xvQ; XLOAD(xvQ, 1, s);
      if (s > 0) { FIN(1, s-1, 64) }
      ACCB(aP)
      f32x4 voQ = zero4;
      KSTEP(aP, arP, 0, GEL(aQ, hQ, xvQ, voQ, 0, 0))
      KSTEP(aP, arP, 1, GEL(aQ, hQ, xvQ, voQ, 0, 1) PUBP(hQ, 1, 0, 0))
      KSTEP(aP, arP, 2, GEL(aQ, hQ, xvQ, voQ, 0, 2))
      KSTEP(aP, arP, 3, GEL(aQ, hQ, xvQ, voQ, 0, 3) PUBP(hQ, 1, 0, 2))
      KSTEP(aP, arP, 4, GEL(aQ, hQ, xvQ, voQ, 1, 0))
      KSTEP(aP, arP, 5, GEL(aQ, hQ, xvQ, voQ, 1, 1) PUBP(hQ, 1, 1, 0))
      KSTEP(aP, arP, 6, GEL(aQ, hQ, xvQ, voQ, 1, 2))
      KSTEP(aP, arP, 7, GEL(aQ, hQ, xvQ, voQ, 1, 3) PUBP(hQ, 1, 1, 2))
      VORED(voQ, 1, s)
      barrier_lgkm();
    }
  }

  // ======== interval B(1023): MFMA(Q,1023) + gates(P,1023) + fin(P,1022) ========
  {
    const int s = T_LEN - 1;
    f32x4 xvP; XLOAD(xvP, 0, s);
    FIN(0, s-1, 0)
    ACCB(aQ)
    f32x4 voP = zero4;
    KSTEP(aQ, arQ, 0, GEL(aP, hP, xvP, voP, 0, 0))
    KSTEP(aQ, arQ, 1, GEL(aP, hP, xvP, voP, 0, 1) PUBP(hP, 0, 0, 0))
    KSTEP(aQ, arQ, 2, GEL(aP, hP, xvP, voP, 0, 2))
    KSTEP(aQ, arQ, 3, GEL(aP, hP, xvP, voP, 0, 3) PUBP(hP, 0, 0, 2))
    KSTEP(aQ, arQ, 4, GEL(aP, hP, xvP, voP, 1, 0))
    KSTEP(aQ, arQ, 5, GEL(aP, hP, xvP, voP, 1, 1) PUBP(hP, 0, 1, 0))
    KSTEP(aQ, arQ, 6, GEL(aP, hP, xvP, voP, 1, 2))
    KSTEP(aQ, arQ, 7, GEL(aP, hP, xvP, voP, 1, 3) PUBP(hP, 0, 1, 2))
    VORED(voP, 0, s)
    barrier_lgkm();
  }
  // ======== epilogue interval: gates(Q,1023) + fin(Q,1022) ========
  {
    const int s = T_LEN - 1;
    f32x4 xvQ; XLOAD(xvQ, 1, s);
    FIN(1, s-1, 64)
    f32x4 voQ = zero4;
    GEL(aQ, hQ, xvQ, voQ, 0, 0)
    GEL(aQ, hQ, xvQ, voQ, 0, 1)
    GEL(aQ, hQ, xvQ, voQ, 0, 2)
    GEL(aQ, hQ, xvQ, voQ, 0, 3)
    GEL(aQ, hQ, xvQ, voQ, 1, 0)
    GEL(aQ, hQ, xvQ, voQ, 1, 1)
    GEL(aQ, hQ, xvQ, voQ, 1, 2)
    GEL(aQ, hQ, xvQ, voQ, 1, 3)
    VORED(voQ, 1, s)
    barrier_lgkm();
  }
  // ======== final finalizes: (P,1023) and (Q,1023) ========
  FIN(0, T_LEN - 1, 0)
  FIN(1, T_LEN - 1, 64)
}

extern "C" void kernel_launch(void* const* d_in, const int* in_sizes, int n_in,
                              void* d_out, int out_size, void* d_ws, size_t ws_size,
                              hipStream_t stream) {
  const float* x     = (const float*)d_in[0];
  const float* w_ih  = (const float*)d_in[1];
  const float* w_hh  = (const float*)d_in[2];
  const float* b_ih  = (const float*)d_in[3];
  const float* b_hh  = (const float*)d_in[4];
  const float* w_out = (const float*)d_in[5];
  const float* b_out = (const float*)d_in[6];
  float* out = (float*)d_out;

  prep_w<<<768, 256, 0, stream>>>(w_hh);
  gru_kernel<<<NBLOCKS, NTHREADS, 0, stream>>>(x, w_ih, b_ih, b_hh, w_out, b_out, out);
}

// Round 5
// 7706.127 us; speedup vs baseline: 1.0310x; 1.0310x over previous
//
#include <hip/hip_runtime.h>

// Persistent batched-GRU kernel for MI355X (gfx950), round 14.
// r13 post-mortem: diet cut VALUBusy 63->47% but wall identical -> interval is
// latency-bound, not pipe-bound. Suspect: r12 dropped r9's x staging; each
// wave issues 16 scattered 4B global loads (4KB stride) per interval, 8x
// redundant per block, consumed immediately -> exposed L2/HBM latency every
// interval. Round-14: restore x chunk-staging via LDS (two-group version):
//  - x_buf[2][32t x 36] f32 (9.2 KB): both groups' 32 rows per t-slot.
//  - refill once per 32 intervals: 2 coalesced loads/thread issued at
//    interval START (B-interval, tr==1), ds_written at interval END ->
//    latency hidden under 48 MFMAs.
//  - per-interval xv = one broadcast ds_read_b128 (conflict-free) instead of
//    4 scattered global loads.
// Carried from r13: two-group pipeline, diet gate math (pre-scaled weights,
// bias-preloaded accs, rcp(1+exp2)), cvt_pk publishes, z_j1/n_j1 in LDS,
// lgkm-only barrier. LDS total 159.2 KB (1 block/CU).

#define B_TOTAL 16384
#define T_LEN   1024
#define GRPROWS 16
#define M_ROWS  32
#define NBLOCKS (B_TOTAL / M_ROWS)      // 512 blocks; 2 sequential per CU
#define NTHREADS 512                    // 8 waves
#define LDSW    264                     // h row stride in shorts
#define TCH     32                      // x chunk length (t steps)
#define NCH     (T_LEN / TCH)           // 32
#define XSTR    36                      // x_buf t-row stride in floats (32 rows + pad, 16B-aligned)

typedef short short8 __attribute__((ext_vector_type(8)));
typedef float f32x4  __attribute__((ext_vector_type(4)));

__device__ unsigned short g_wsw[196608];   // swizzled, PRE-SCALED bf16 W_hh

__device__ __forceinline__ unsigned short f2b(float f) {
  unsigned u = __builtin_bit_cast(unsigned, f);
  u += 0x7fffu + ((u >> 16) & 1u);
  return (unsigned short)(u >> 16);
}
__device__ __forceinline__ unsigned cvt_pk_bf16(float lo, float hi) {
  unsigned r;
  asm("v_cvt_pk_bf16_f32 %0, %1, %2" : "=v"(r) : "v"(lo), "v"(hi));
  return r;
}
// sum over a 16-lane DPP row; result valid in the LAST lane (r16==15)
__device__ __forceinline__ float dpp_red16(float v) {
  int x = __builtin_bit_cast(int, v);
  v += __builtin_bit_cast(float, __builtin_amdgcn_update_dpp(0, x, 0x118, 0xF, 0xF, true)); // row_shr:8
  x = __builtin_bit_cast(int, v);
  v += __builtin_bit_cast(float, __builtin_amdgcn_update_dpp(0, x, 0x114, 0xF, 0xF, true)); // row_shr:4
  x = __builtin_bit_cast(int, v);
  v += __builtin_bit_cast(float, __builtin_amdgcn_update_dpp(0, x, 0x112, 0xF, 0xF, true)); // row_shr:2
  x = __builtin_bit_cast(int, v);
  v += __builtin_bit_cast(float, __builtin_amdgcn_update_dpp(0, x, 0x111, 0xF, 0xF, true)); // row_shr:1
  return v;
}
// barrier draining LDS only (no vmcnt(0): global stores stay in flight)
__device__ __forceinline__ void barrier_lgkm() {
  asm volatile("s_waitcnt lgkmcnt(0)\n\ts_barrier" ::: "memory");
}

// Swizzle W_hh (768x256 f32 row-major) into fragment-major bf16, PRE-SCALED:
// rows 0..511 (r,z) * -log2e ; rows 512..767 (n) * 2*log2e.
__global__ void prep_w(const float* __restrict__ w_hh) {
  int tid  = blockIdx.x * 256 + threadIdx.x;     // 196608 total
  int e    = tid & 7;
  int lane = (tid >> 3) & 63;
  int ks   = (tid >> 9) & 7;
  int nt   = tid >> 12;
  int row  = nt * 16 + (lane & 15);
  int col  = ks * 32 + (lane >> 4) * 8 + e;
  float s  = (row < 512) ? -1.44269504f : 2.88539008f;
  g_wsw[tid] = f2b(w_hh[row * 256 + col] * s);
}

#define MF(A, B, C) __builtin_amdgcn_mfma_f32_16x16x32_bf16((A), (B), (C), 0, 0, 0)

// one K-step for acc-set P## (6 chains): 4 register B-frags + 2 LDS B-frags,
// EXTRA = interleaved gate work for the other group
#define KSTEP(P, AR, KS, EXTRA)  {                                             \
    short8 a_  = *(const short8*)((AR) + (KS)*32);                             \
    short8 z1_ = *(const short8*)&w_lds[wz1b + (KS)*512];                      \
    short8 n1_ = *(const short8*)&w_lds[wn1b + (KS)*512];                      \
    P##00 = MF(a_, wrr0[KS], P##00);                                           \
    P##01 = MF(a_, wrr1[KS], P##01);                                           \
    P##10 = MF(a_, wrz0[KS], P##10);                                           \
    P##11 = MF(a_, z1_,      P##11);                                           \
    P##20 = MF(a_, wrn0[KS], P##20);                                           \
    P##21 = MF(a_, n1_,      P##21);                                           \
    EXTRA                                                                      \
  }

// one gate element, DIET math (accs carry fused scaled biases).
#define GEL(AC, HR, XV, VO, J, I) {                                            \
    float t_r = __builtin_fmaf(XV[I], swr[J], AC##0##J[I]);                    \
    float rg_ = __builtin_amdgcn_rcpf(1.0f + __builtin_amdgcn_exp2f(t_r));     \
    float t_z = __builtin_fmaf(XV[I], swz[J], AC##1##J[I]);                    \
    float zg_ = __builtin_amdgcn_rcpf(1.0f + __builtin_amdgcn_exp2f(t_z));     \
    float t_n = __builtin_fmaf(XV[I], swn[J], sbni[J]);                        \
    float yn_ = __builtin_fmaf(rg_, AC##2##J[I], t_n);                         \
    float rn_ = __builtin_amdgcn_rcpf(1.0f + __builtin_amdgcn_exp2f(yn_));     \
    float ng_ = __builtin_fmaf(-2.0f, rn_, 1.0f);                              \
    float hn_ = __builtin_fmaf(zg_, HR[J][I] - ng_, ng_);                      \
    HR[J][I] = hn_;                                                            \
    VO[I] += fmaxf(hn_, 0.0f)*wo[J];                                           \
  }

// publish rows (I0, I0+1) of column c(J) for group HG as a packed bf16 pair
#define PUBP(HR, HG, J, I0) {                                                  \
    unsigned pk_ = cvt_pk_bf16(HR[J][I0], HR[J][(I0)+1]);                      \
    h_lds[HG][hwb[J] + (I0)*LDSW]     = (unsigned short)pk_;                   \
    h_lds[HG][hwb[J] + ((I0)+1)*LDSW] = (unsigned short)(pk_ >> 16);           \
  }

#define VORED(VO, G, S) {                                                      \
    _Pragma("unroll") for (int i_ = 0; i_ < 4; ++i_) VO[i_] = dpp_red16(VO[i_]); \
    if (r16 == 15) {                                                           \
      _Pragma("unroll") for (int i_ = 0; i_ < 4; ++i_)                         \
        op[G][(S)&1][w][q*4 + i_] = VO[i_];                                    \
    } }

// finalize out(G, S): 16 threads starting at TLO sum 8 wave partials + store
#define FIN(G, S, TLO)                                                         \
  if (tid >= (TLO) && tid < (TLO) + 16) {                                      \
    float o_ = bo;                                                             \
    _Pragma("unroll") for (int ww_ = 0; ww_ < 8; ++ww_)                        \
      o_ += op[G][(S)&1][ww_][tid - (TLO)];                                    \
    out[(base + (G)*GRPROWS + (tid - (TLO)))*T_LEN + (S)] = o_;                \
  }

// acc init: fused scaled biases (r in acc0, z in acc1, n-hh in acc2)
#define ACCB(P) {                                                              \
    P##00 = (f32x4){sbr[0],sbr[0],sbr[0],sbr[0]};                              \
    P##01 = (f32x4){sbr[1],sbr[1],sbr[1],sbr[1]};                              \
    P##10 = (f32x4){sbz[0],sbz[0],sbz[0],sbz[0]};                              \
    P##11 = (f32x4){sbz[1],sbz[1],sbz[1],sbz[1]};                              \
    P##20 = (f32x4){sbnh[0],sbnh[0],sbnh[0],sbnh[0]};                          \
    P##21 = (f32x4){sbnh[1],sbnh[1],sbnh[1],sbnh[1]};                          \
  }

// broadcast read of 4 x values for group G from x_buf (conflict-free)
#define XREAD(XV, G, XP, TR)                                                   \
  XV = *(const f32x4*)&x_buf[XP][(TR)*XSTR + (G)*GRPROWS + q*4];

__global__ __launch_bounds__(NTHREADS, 2) void gru_kernel(
    const float* __restrict__ x,
    const float* __restrict__ w_ih,
    const float* __restrict__ b_ih,
    const float* __restrict__ b_hh,
    const float* __restrict__ w_out,
    const float* __restrict__ b_out,
    float* __restrict__ out)
{
  __shared__ unsigned short h_lds[2][GRPROWS * LDSW];  // [group], 16.5 KB
  __shared__ unsigned short w_lds[16 * 8 * 512];       // z_j1/n_j1 frags, 128 KB
  __shared__ float op[2][2][8][GRPROWS];               // [group][phase][wave][row], 2 KB
  __shared__ float x_buf[2][TCH * XSTR];               // x chunks [t][row 0..31], 9.2 KB

  const int tid  = threadIdx.x;
  const int w    = tid >> 6;        // wave 0..7
  const int lane = tid & 63;
  const int r16  = lane & 15;
  const int q    = lane >> 4;
  const long base = (long)blockIdx.x * M_ROWS;

  for (int i = tid; i < 2 * GRPROWS * LDSW; i += NTHREADS) h_lds[0][i] = 0;  // h0 = 0 (both groups)

  // ---- stage z_j1 (gsel 0) and n_j1 (gsel 1) frags into LDS ----
  const int wz1b = ((w*2 + 0)*8)*512 + lane*8;
  const int wn1b = ((w*2 + 1)*8)*512 + lane*8;
#pragma unroll
  for (int gsel = 0; gsel < 2; ++gsel)
#pragma unroll
    for (int ks = 0; ks < 8; ++ks)
      *(short8*)&w_lds[((w*2 + gsel)*8 + ks)*512 + lane*8] =
        *(const short8*)&g_wsw[((((gsel + 1)*16 + w*2 + 1)*8 + ks)*64 + lane)*8];

  // ---- register-resident frags: r_j0, r_j1, z_j0, n_j0 (128 VGPR) ----
  short8 wrr0[8], wrr1[8], wrz0[8], wrn0[8];
#pragma unroll
  for (int ks = 0; ks < 8; ++ks) {
    wrr0[ks] = *(const short8*)&g_wsw[(((0*16 + w*2 + 0)*8 + ks)*64 + lane)*8];
    wrr1[ks] = *(const short8*)&g_wsw[(((0*16 + w*2 + 1)*8 + ks)*64 + lane)*8];
    wrz0[ks] = *(const short8*)&g_wsw[(((1*16 + w*2 + 0)*8 + ks)*64 + lane)*8];
    wrn0[ks] = *(const short8*)&g_wsw[(((2*16 + w*2 + 0)*8 + ks)*64 + lane)*8];
  }

  // per-lane constants for cols c(j) = w*32 + j*16 + r16, pre-scaled:
  // r,z: -log2e ; n: +2*log2e
  const float C1 = 1.44269504f;
  float swr[2], swz[2], swn[2], sbr[2], sbz[2], sbni[2], sbnh[2], wo[2];
  int hwb[2];
#pragma unroll
  for (int j = 0; j < 2; ++j) {
    int c = w*32 + j*16 + r16;
    hwb[j]   = (q*4)*LDSW + c;
    swr[j]   = -C1 * w_ih[c];
    swz[j]   = -C1 * w_ih[256 + c];
    swn[j]   = 2.0f * C1 * w_ih[512 + c];
    sbr[j]   = -C1 * (b_ih[c]       + b_hh[c]);
    sbz[j]   = -C1 * (b_ih[256 + c] + b_hh[256 + c]);
    sbni[j]  = 2.0f * C1 * b_ih[512 + c];
    sbnh[j]  = 2.0f * C1 * b_hh[512 + c];
    wo[j]    = w_out[c];
  }
  const float bo = b_out[0];
  const f32x4 zero4 = {0.f, 0.f, 0.f, 0.f};

  float hP[2][4], hQ[2][4];        // f32 h carry, both groups
#pragma unroll
  for (int j = 0; j < 2; ++j)
#pragma unroll
    for (int i = 0; i < 4; ++i) { hP[j][i] = 0.0f; hQ[j][i] = 0.0f; }

  const unsigned short* arP = &h_lds[0][r16*LDSW + q*8];
  const unsigned short* arQ = &h_lds[1][r16*LDSW + q*8];

  // x staging indices: thread -> (row = tid>>5 in 0..15, t-slot = tid&31)
  const int xrow = tid >> 5;
  const int xts  = tid & 31;

  // prefill x chunk 0 (both groups; coalesced 32-wide per row)
  x_buf[0][xts*XSTR + xrow]           = x[(base + xrow)*T_LEN + xts];
  x_buf[0][xts*XSTR + GRPROWS + xrow] = x[(base + GRPROWS + xrow)*T_LEN + xts];

  // acc sets: aP## built in A-intervals / consumed in B; aQ## vice versa
  f32x4 aP00, aP01, aP10, aP11, aP20, aP21;
  f32x4 aQ00, aQ01, aQ10, aQ11, aQ20, aQ21;

  barrier_lgkm();   // h zeros + w_lds + x chunk 0 staged

  // ---- pre-loop interval A0: MFMA(P, 0) only ----
  {
    ACCB(aP)
    KSTEP(aP, arP, 0, ) KSTEP(aP, arP, 1, ) KSTEP(aP, arP, 2, ) KSTEP(aP, arP, 3, )
    KSTEP(aP, arP, 4, ) KSTEP(aP, arP, 5, ) KSTEP(aP, arP, 6, ) KSTEP(aP, arP, 7, )
    barrier_lgkm();
  }

#pragma unroll 1
  for (int s = 0; s < T_LEN - 1; ++s) {     // s = 0..1022
    const int tr = s & (TCH - 1);
    const int tc = s >> 5;
    const int xp = tc & 1;
    const int refill = (tr == 1) && (tc + 1 < NCH);

    // ======== interval B(s): MFMA(Q,s) + gates(P,s) + fin(P,s-1) ========
    {
      // x refill: issue coalesced loads NOW, ds_write at interval end
      float xa, xb;
      if (refill) {
        const long t2 = (long)(tc + 1)*TCH + xts;
        xa = x[(base + xrow)*T_LEN + t2];
        xb = x[(base + GRPROWS + xrow)*T_LEN + t2];
      }
      f32x4 xvP; XREAD(xvP, 0, xp, tr)
      if (s > 0) { FIN(0, s-1, 0) }
      ACCB(aQ)
      f32x4 voP = zero4;
      KSTEP(aQ, arQ, 0, GEL(aP, hP, xvP, voP, 0, 0))
      KSTEP(aQ, arQ, 1, GEL(aP, hP, xvP, voP, 0, 1) PUBP(hP, 0, 0, 0))
      KSTEP(aQ, arQ, 2, GEL(aP, hP, xvP, voP, 0, 2))
      KSTEP(aQ, arQ, 3, GEL(aP, hP, xvP, voP, 0, 3) PUBP(hP, 0, 0, 2))
      KSTEP(aQ, arQ, 4, GEL(aP, hP, xvP, voP, 1, 0))
      KSTEP(aQ, arQ, 5, GEL(aP, hP, xvP, voP, 1, 1) PUBP(hP, 0, 1, 0))
      KSTEP(aQ, arQ, 6, GEL(aP, hP, xvP, voP, 1, 2))
      KSTEP(aQ, arQ, 7, GEL(aP, hP, xvP, voP, 1, 3) PUBP(hP, 0, 1, 2))
      VORED(voP, 0, s)
      if (refill) {
        x_buf[xp ^ 1][xts*XSTR + xrow]           = xa;
        x_buf[xp ^ 1][xts*XSTR + GRPROWS + xrow] = xb;
      }
      barrier_lgkm();
    }
    // ======== interval A(s+1): MFMA(P,s+1) + gates(Q,s) + fin(Q,s-1) ========
    {
      f32x4 xvQ; XREAD(xvQ, 1, xp, tr)
      if (s > 0) { FIN(1, s-1, 64) }
      ACCB(aP)
      f32x4 voQ = zero4;
      KSTEP(aP, arP, 0, GEL(aQ, hQ, xvQ, voQ, 0, 0))
      KSTEP(aP, arP, 1, GEL(aQ, hQ, xvQ, voQ, 0, 1) PUBP(hQ, 1, 0, 0))
      KSTEP(aP, arP, 2, GEL(aQ, hQ, xvQ, voQ, 0, 2))
      KSTEP(aP, arP, 3, GEL(aQ, hQ, xvQ, voQ, 0, 3) PUBP(hQ, 1, 0, 2))
      KSTEP(aP, arP, 4, GEL(aQ, hQ, xvQ, voQ, 1, 0))
      KSTEP(aP, arP, 5, GEL(aQ, hQ, xvQ, voQ, 1, 1) PUBP(hQ, 1, 1, 0))
      KSTEP(aP, arP, 6, GEL(aQ, hQ, xvQ, voQ, 1, 2))
      KSTEP(aP, arP, 7, GEL(aQ, hQ, xvQ, voQ, 1, 3) PUBP(hQ, 1, 1, 2))
      VORED(voQ, 1, s)
      barrier_lgkm();
    }
  }

  // ======== interval B(1023): MFMA(Q,1023) + gates(P,1023) + fin(P,1022) ========
  {
    const int s = T_LEN - 1;                 // tr=31, tc=31, xp=1
    f32x4 xvP; XREAD(xvP, 0, 1, TCH - 1)
    FIN(0, s-1, 0)
    ACCB(aQ)
    f32x4 voP = zero4;
    KSTEP(aQ, arQ, 0, GEL(aP, hP, xvP, voP, 0, 0))
    KSTEP(aQ, arQ, 1, GEL(aP, hP, xvP, voP, 0, 1) PUBP(hP, 0, 0, 0))
    KSTEP(aQ, arQ, 2, GEL(aP, hP, xvP, voP, 0, 2))
    KSTEP(aQ, arQ, 3, GEL(aP, hP, xvP, voP, 0, 3) PUBP(hP, 0, 0, 2))
    KSTEP(aQ, arQ, 4, GEL(aP, hP, xvP, voP, 1, 0))
    KSTEP(aQ, arQ, 5, GEL(aP, hP, xvP, voP, 1, 1) PUBP(hP, 0, 1, 0))
    KSTEP(aQ, arQ, 6, GEL(aP, hP, xvP, voP, 1, 2))
    KSTEP(aQ, arQ, 7, GEL(aP, hP, xvP, voP, 1, 3) PUBP(hP, 0, 1, 2))
    VORED(voP, 0, s)
    barrier_lgkm();
  }
  // ======== epilogue interval: gates(Q,1023) + fin(Q,1022) ========
  {
    const int s = T_LEN - 1;
    f32x4 xvQ; XREAD(xvQ, 1, 1, TCH - 1)
    FIN(1, s-1, 64)
    f32x4 voQ = zero4;
    GEL(aQ, hQ, xvQ, voQ, 0, 0)
    GEL(aQ, hQ, xvQ, voQ, 0, 1)
    GEL(aQ, hQ, xvQ, voQ, 0, 2)
    GEL(aQ, hQ, xvQ, voQ, 0, 3)
    GEL(aQ, hQ, xvQ, voQ, 1, 0)
    GEL(aQ, hQ, xvQ, voQ, 1, 1)
    GEL(aQ, hQ, xvQ, voQ, 1, 2)
    GEL(aQ, hQ, xvQ, voQ, 1, 3)
    VORED(voQ, 1, s)
    barrier_lgkm();
  }
  // ======== final finalizes: (P,1023) and (Q,1023) ========
  FIN(0, T_LEN - 1, 0)
  FIN(1, T_LEN - 1, 64)
}

extern "C" void kernel_launch(void* const* d_in, const int* in_sizes, int n_in,
                              void* d_out, int out_size, void* d_ws, size_t ws_size,
                              hipStream_t stream) {
  const float* x     = (const float*)d_in[0];
  const float* w_ih  = (const float*)d_in[1];
  const float* w_hh  = (const float*)d_in[2];
  const float* b_ih  = (const float*)d_in[3];
  const float* b_hh  = (const float*)d_in[4];
  const float* w_out = (const float*)d_in[5];
  const float* b_out = (const float*)d_in[6];
  float* out = (float*)d_out;

  prep_w<<<768, 256, 0, stream>>>(w_hh);
  gru_kernel<<<NBLOCKS, NTHREADS, 0, stream>>>(x, w_ih, b_ih, b_hh, w_out, b_out, out);
}